// Round 10
// baseline (482.690 us; speedup 1.0000x reference)
//
#include <hip/hip_runtime.h>

typedef __attribute__((ext_vector_type(8))) short short8;
typedef __attribute__((ext_vector_type(4))) float floatx4;

__device__ __forceinline__ unsigned short f2b(float f) {
  unsigned int u = __float_as_uint(f);
  unsigned int r = (u + 0x7FFFu + ((u >> 16) & 1u)) >> 16;  // RNE
  return (unsigned short)r;
}
__device__ __forceinline__ unsigned int pk2(float a, float b) {
  return (unsigned int)f2b(a) | ((unsigned int)f2b(b) << 16);
}
// load 8 fp32 -> 8 bf16 packed in a uint4
__device__ __forceinline__ uint4 ld8f(const float* p) {
  float4 a = *(const float4*)p;
  float4 b = *(const float4*)(p + 4);
  uint4 r;
  r.x = pk2(a.x, a.y); r.y = pk2(a.z, a.w);
  r.z = pk2(b.x, b.y); r.w = pk2(b.z, b.w);
  return r;
}

// async global->LDS, 16B per lane
#define GLL(g, l) __builtin_amdgcn_global_load_lds( \
    (const __attribute__((address_space(1))) unsigned int*)(g), \
    (__attribute__((address_space(3))) unsigned int*)(l), 16, 0, 0)

// XCD-bijective swizzle (3D). Requires nwg % 8 == 0 (384/256/128: all ok).
__device__ __forceinline__ void xcd_swz(int& bx, int& by, int& bz) {
  const int nx = gridDim.x, ny = gridDim.y;
  const int nwg = nx * ny * gridDim.z;
  const int lbid = blockIdx.x + nx * (blockIdx.y + ny * blockIdx.z);
  const int s = (lbid & 7) * (nwg >> 3) + (lbid >> 3);
  bx = s % nx; by = (s / nx) % ny; bz = s / (nx * ny);
}

// ---------------------------------------------------------------------------
// 8-phase 256x256 K-loop (m198/m201 schedule, plain-HIP port).
// r1-r9 lesson: every "2-phase" schedule (one MFMA cluster between 2 barriers
// per K-step) pinned at ~9-12% MfmaUtil regardless of occupancy/prefetch/
// conflicts. This is the catalog's proven escape: fine-grained phase
// interleave + counted vmcnt that never drains in steady state.
// Geometry: 512 thr / 8 waves (2Mx4N), wave out 128x64 (acc[8][4]); BK=64 as
// two 32-k halves. LDS: per matrix a 4-slot ring of half-tiles
// [256 rows][32 k] bf16 (16KB/slot) -> 64KB A + 64KB B = 128KB (dynamic).
// Half-tile of tile t, k-half h lives in slot (2t+h)&3.
// Per K-tile, 4 phases: ph0 (kh0,rows0-63) stages A-kh1(t+1); ph1 (kh0,
// rows64-127, B-frags reused) stages B-kh1(t+1) + vmcnt(8); ph2 (kh1,rows
// 0-63) stages A-kh0(t+2); ph3 (kh1,rows64-127) stages B-kh0(t+2) + vmcnt(8).
// Phase body: ds_read -> stage -> s_barrier -> lgkmcnt(0) -> setprio(1) ->
// 16 MFMA -> setprio(0) -> s_barrier.
// Slot safety: each stage overwrites a slot whose last reader phase completed
// a barrier earlier in every wave's program order. vmcnt(8) leaves exactly
// the 4 newest half-tiles in flight; the following barrier makes all waves'
// vmcnt collectively cover the slot. Tail: vmcnt 8 -> 4 -> 0.
// ---------------------------------------------------------------------------
#define STGH(M, L, tt, h) do { \
    const unsigned short* _s = (M) + (size_t)srow * K + (tt) * 64 + (h) * 32 + skc; \
    unsigned short* _d = (L) + (((2 * (tt) + (h)) & 3) * 8192) + ldst; \
    GLL(_s, _d); \
    GLL(_s + (size_t)128 * K, _d + 4096); \
  } while (0)

__device__ __forceinline__ void kloop8p(const unsigned short* __restrict__ A,
                                        const unsigned short* __restrict__ B,
                                        int K, unsigned short* lds,
                                        floatx4 (&acc)[8][4])
{
  unsigned short* LA = lds;            // 4 slots x 8192 shorts
  unsigned short* LB = lds + 32768;    // 4 slots x 8192 shorts
  const int tid = threadIdx.x;
  const int lane = tid & 63, w = tid >> 6;
  const int quad = lane >> 4, l16 = lane & 15;
  const int wr = w >> 2, wc = w & 3;
  const int srow = tid >> 2;           // staging row 0..127 (+128 for 2nd GLL)
  const int skc = (tid & 3) * 8;       // staging k-chunk within 32-k half
  const int ldst = tid * 8;            // linear LDS dest within slot
  const int NT = K >> 6;

  // prologue: A0(0) B0(0) A1(0) B1(0) A0(1) B0(1) -> 12 insts in flight
  STGH(A, LA, 0, 0); STGH(B, LB, 0, 0);
  STGH(A, LA, 0, 1); STGH(B, LB, 0, 1);
  STGH(A, LA, 1, 0); STGH(B, LB, 1, 0);
  asm volatile("s_waitcnt vmcnt(8)" ::: "memory");   // kh0(0) landed
  __builtin_amdgcn_s_barrier();
  __builtin_amdgcn_sched_barrier(0);

  for (int t = 0; t < NT; ++t) {
    const int s0 = ((2 * t) & 3) * 8192;       // kh0 slot
    const int s1 = ((2 * t + 1) & 3) * 8192;   // kh1 slot
    short8 af[4], bf[4];

    // ---------------- phase 0: kh0, rows 0-63 ----------------
#pragma unroll
    for (int i = 0; i < 4; i++)
      af[i] = *(const short8*)&LA[s0 + (wr * 128 + i * 16 + l16) * 32 + quad * 8];
#pragma unroll
    for (int j = 0; j < 4; j++)
      bf[j] = *(const short8*)&LB[s0 + (wc * 64 + j * 16 + l16) * 32 + quad * 8];
    if (t + 1 < NT) STGH(A, LA, t + 1, 1);
    __builtin_amdgcn_s_barrier();
    asm volatile("s_waitcnt lgkmcnt(0)" ::: "memory");
    __builtin_amdgcn_sched_barrier(0);
    __builtin_amdgcn_s_setprio(1);
#pragma unroll
    for (int i = 0; i < 4; i++)
#pragma unroll
      for (int j = 0; j < 4; j++)
        acc[i][j] = __builtin_amdgcn_mfma_f32_16x16x32_bf16(af[i], bf[j], acc[i][j], 0, 0, 0);
    __builtin_amdgcn_s_setprio(0);
    __builtin_amdgcn_s_barrier();
    __builtin_amdgcn_sched_barrier(0);

    // ---------------- phase 1: kh0, rows 64-127 (bf reused) ----------------
#pragma unroll
    for (int i = 0; i < 4; i++)
      af[i] = *(const short8*)&LA[s0 + (wr * 128 + 64 + i * 16 + l16) * 32 + quad * 8];
    if (t + 1 < NT) {
      STGH(B, LB, t + 1, 1);
      asm volatile("s_waitcnt vmcnt(8)" ::: "memory");
    } else {
      asm volatile("s_waitcnt vmcnt(0)" ::: "memory");
    }
    __builtin_amdgcn_s_barrier();
    asm volatile("s_waitcnt lgkmcnt(0)" ::: "memory");
    __builtin_amdgcn_sched_barrier(0);
    __builtin_amdgcn_s_setprio(1);
#pragma unroll
    for (int i = 0; i < 4; i++)
#pragma unroll
      for (int j = 0; j < 4; j++)
        acc[4 + i][j] = __builtin_amdgcn_mfma_f32_16x16x32_bf16(af[i], bf[j], acc[4 + i][j], 0, 0, 0);
    __builtin_amdgcn_s_setprio(0);
    __builtin_amdgcn_s_barrier();
    __builtin_amdgcn_sched_barrier(0);

    // ---------------- phase 2: kh1, rows 0-63 ----------------
#pragma unroll
    for (int i = 0; i < 4; i++)
      af[i] = *(const short8*)&LA[s1 + (wr * 128 + i * 16 + l16) * 32 + quad * 8];
#pragma unroll
    for (int j = 0; j < 4; j++)
      bf[j] = *(const short8*)&LB[s1 + (wc * 64 + j * 16 + l16) * 32 + quad * 8];
    if (t + 2 < NT) STGH(A, LA, t + 2, 0);
    __builtin_amdgcn_s_barrier();
    asm volatile("s_waitcnt lgkmcnt(0)" ::: "memory");
    __builtin_amdgcn_sched_barrier(0);
    __builtin_amdgcn_s_setprio(1);
#pragma unroll
    for (int i = 0; i < 4; i++)
#pragma unroll
      for (int j = 0; j < 4; j++)
        acc[i][j] = __builtin_amdgcn_mfma_f32_16x16x32_bf16(af[i], bf[j], acc[i][j], 0, 0, 0);
    __builtin_amdgcn_s_setprio(0);
    __builtin_amdgcn_s_barrier();
    __builtin_amdgcn_sched_barrier(0);

    // ---------------- phase 3: kh1, rows 64-127 (bf reused) ----------------
#pragma unroll
    for (int i = 0; i < 4; i++)
      af[i] = *(const short8*)&LA[s1 + (wr * 128 + 64 + i * 16 + l16) * 32 + quad * 8];
    if (t + 2 < NT) {
      STGH(B, LB, t + 2, 0);
      asm volatile("s_waitcnt vmcnt(8)" ::: "memory");
    } else if (t + 1 < NT) {
      asm volatile("s_waitcnt vmcnt(4)" ::: "memory");   // kh0(t+1) landed
    } else {
      asm volatile("s_waitcnt vmcnt(0)" ::: "memory");
    }
    __builtin_amdgcn_s_barrier();
    asm volatile("s_waitcnt lgkmcnt(0)" ::: "memory");
    __builtin_amdgcn_sched_barrier(0);
    __builtin_amdgcn_s_setprio(1);
#pragma unroll
    for (int i = 0; i < 4; i++)
#pragma unroll
      for (int j = 0; j < 4; j++)
        acc[4 + i][j] = __builtin_amdgcn_mfma_f32_16x16x32_bf16(af[i], bf[j], acc[4 + i][j], 0, 0, 0);
    __builtin_amdgcn_s_setprio(0);
    __builtin_amdgcn_s_barrier();
    __builtin_amdgcn_sched_barrier(0);
  }
}

#define ACC_INIT floatx4 acc[8][4]; \
  _Pragma("unroll") for (int i = 0; i < 8; i++) \
  _Pragma("unroll") for (int j = 0; j < 4; j++) acc[i][j] = (floatx4){0.f, 0.f, 0.f, 0.f};

// ---- fused QKV: C[16384,1536] split into q/k/v [16384,512] each
__global__ __launch_bounds__(512, 2) void gemm_qkv(
    const unsigned short* __restrict__ x,   // [16384,512] bf16
    const unsigned short* __restrict__ WT,  // [1536,512] bf16 (Wq^T;Wk^T;Wv^T)
    const float* __restrict__ bq, const float* __restrict__ bk, const float* __restrict__ bv,
    unsigned short* __restrict__ q, unsigned short* __restrict__ kx, unsigned short* __restrict__ v)
{
  extern __shared__ unsigned short smem[];
  int bx, by, bz;
  xcd_swz(bx, by, bz);
  const int m0 = by * 256, n0 = bx * 256;   // 256-tile lies in one 512 segment
  ACC_INIT
  kloop8p(x + (size_t)m0 * 512, WT + (size_t)n0 * 512, 512, smem, acc);

  const int seg = n0 >> 9, nloc = n0 & 511;
  unsigned short* C = seg == 0 ? q : (seg == 1 ? kx : v);
  const float* bias = seg == 0 ? bq : (seg == 1 ? bk : bv);
  const int lane = threadIdx.x & 63, w = threadIdx.x >> 6;
  const int quad = lane >> 4, l16 = lane & 15, wr = w >> 2, wc = w & 3;
  float bvv[4];
#pragma unroll
  for (int j = 0; j < 4; j++) bvv[j] = bias[nloc + wc * 64 + j * 16 + l16];
#pragma unroll
  for (int i = 0; i < 8; i++)
#pragma unroll
    for (int r = 0; r < 4; r++) {
      int m = m0 + wr * 128 + i * 16 + quad * 4 + r;
      unsigned short* crow = C + (size_t)m * 512 + nloc + wc * 64 + l16;
#pragma unroll
      for (int j = 0; j < 4; j++) crow[j * 16] = f2b(acc[i][j][r] + bvv[j]);
    }
}

// ---- generic bf16 GEMM: C = act(A @ Bt^T + bias), C fp32 (CF32) or bf16
template<int CF32, int ACT>
__global__ __launch_bounds__(512, 2) void gemm2(
    const unsigned short* __restrict__ A, const unsigned short* __restrict__ Bt,
    const float* __restrict__ bias, void* __restrict__ Cv,
    int N, int K, long aB, long bB, long cB)
{
  extern __shared__ unsigned short smem[];
  int bx, by, bz;
  xcd_swz(bx, by, bz);
  const int b = bz;
  const int m0 = by * 256, n0 = bx * 256;
  ACC_INIT
  kloop8p(A + (size_t)b * aB + (size_t)m0 * K, Bt + (size_t)b * bB + (size_t)n0 * K,
          K, smem, acc);

  const int lane = threadIdx.x & 63, w = threadIdx.x >> 6;
  const int quad = lane >> 4, l16 = lane & 15, wr = w >> 2, wc = w & 3;
  float bvv[4];
#pragma unroll
  for (int j = 0; j < 4; j++)
    bvv[j] = bias ? bias[n0 + wc * 64 + j * 16 + l16] : 0.f;
  float*          Cf = (float*)Cv          + (size_t)b * cB;
  unsigned short* Ch = (unsigned short*)Cv + (size_t)b * cB;
#pragma unroll
  for (int i = 0; i < 8; i++)
#pragma unroll
    for (int r = 0; r < 4; r++) {
      int m = m0 + wr * 128 + i * 16 + quad * 4 + r;
      size_t base = (size_t)m * N + n0 + wc * 64 + l16;
#pragma unroll
      for (int j = 0; j < 4; j++) {
        float vv = acc[i][j][r] + bvv[j];
        if (ACT == 1) vv = tanhf(vv);
        if (CF32) Cf[base + j * 16] = vv;
        else      Ch[base + j * 16] = f2b(vv);
      }
    }
}

// ---- score: E = dep ? exp(clamp((q.k)*dept[dep])) : 0, fp32, from regs
__global__ __launch_bounds__(512, 2) void score_kernel(
    const unsigned short* __restrict__ Q, const unsigned short* __restrict__ Km,
    const int* __restrict__ dep, const float* __restrict__ dept,
    float* __restrict__ E)
{
  extern __shared__ unsigned short smem[];
  int bx, by, bz;
  xcd_swz(bx, by, bz);
  const int b = bz;
  const int m0 = by * 256, n0 = bx * 256;
  ACC_INIT
  kloop8p(Q + (size_t)b * (1024 * 512) + (size_t)m0 * 512,
          Km + (size_t)b * (1024 * 512) + (size_t)n0 * 512,
          512, smem, acc);

  const int tid = threadIdx.x;
  const int lane = tid & 63, w = tid >> 6;
  const int quad = lane >> 4, l16 = lane & 15, wr = w >> 2, wc = w & 3;
  const int* depb = dep + (size_t)b * 1024 * 1024;
  float* Eb = E + (size_t)b * 1024 * 1024;
#pragma unroll
  for (int i = 0; i < 8; i++)
#pragma unroll
    for (int r = 0; r < 4; r++) {
      const int m = m0 + wr * 128 + i * 16 + quad * 4 + r;
      const int* dr = depb + (size_t)m * 1024 + n0 + wc * 64 + l16;
      float* er = Eb + (size_t)m * 1024 + n0 + wc * 64 + l16;
#pragma unroll
      for (int j = 0; j < 4; j++) {
        int d = dr[j * 16];
        float s = acc[i][j][r];
        er[j * 16] = d ? __expf(fminf(fmaxf(s * dept[d & 63], -60.f), 60.f)) : 0.f;
      }
    }
}

// ---- x = bf16(embed[inputs]) : one row per 64 lanes, 4 rows/block
__global__ void build_x(const float* __restrict__ embed, const int* __restrict__ inputs,
                        unsigned short* __restrict__ x)
{
  const int row = blockIdx.x * 4 + (threadIdx.x >> 6);
  const int lane = threadIdx.x & 63;
  const float* src = embed + (size_t)inputs[row] * 512 + lane * 8;
  *(uint4*)&x[(size_t)row * 512 + lane * 8] = ld8f(src);
}

// ---- all 5 weight transposes fp32->bf16 in one launch (z selects source)
__global__ void trans_w(const float* s0, const float* s1, const float* s2,
                        const float* s3, const float* s4, unsigned short* dst)
{
  __shared__ unsigned short tile[32][33];
  const int z = blockIdx.z;
  const float* src = z == 0 ? s0 : z == 1 ? s1 : z == 2 ? s2 : z == 3 ? s3 : s4;
  unsigned short* ob = dst + (size_t)z * 262144;
  int c0 = blockIdx.x * 32, r0 = blockIdx.y * 32;
  int tx = threadIdx.x & 31, ty = threadIdx.x >> 5;
  for (int i = ty; i < 32; i += 8)
    tile[i][tx] = f2b(src[(size_t)(r0 + i) * 512 + (c0 + tx)]);
  __syncthreads();
  for (int i = ty; i < 32; i += 8)
    ob[(size_t)(c0 + i) * 512 + (r0 + tx)] = tile[tx][i];
}

// ---- bf16 transpose (v -> vT), batched
__global__ void trans_v(const unsigned short* __restrict__ in, unsigned short* __restrict__ out)
{
  __shared__ unsigned short tile[32][33];
  const unsigned short* ib = in + (size_t)blockIdx.z * (1024 * 512);
  unsigned short* ob = out + (size_t)blockIdx.z * (512 * 1024);
  int c0 = blockIdx.x * 32, r0 = blockIdx.y * 32;
  int tx = threadIdx.x & 31, ty = threadIdx.x >> 5;
  for (int i = ty; i < 32; i += 8)
    tile[i][tx] = ib[(size_t)(r0 + i) * 512 + (c0 + tx)];
  __syncthreads();
  for (int i = ty; i < 32; i += 8)
    ob[(size_t)(c0 + i) * 1024 + (r0 + tx)] = tile[tx][i];
}

// ---- rows /= rowsum; also emit bf16 copy for the PV GEMM
__global__ void normalize_rows(float* __restrict__ wf, unsigned short* __restrict__ wb)
{
  size_t row = blockIdx.x;
  float4* p = (float4*)(wf + row * 1024);
  float4 u = p[threadIdx.x];
  float s = (u.x + u.y) + (u.z + u.w);
#pragma unroll
  for (int d = 1; d < 64; d <<= 1) s += __shfl_xor(s, d);
  __shared__ float acc4[4];
  if ((threadIdx.x & 63) == 0) acc4[threadIdx.x >> 6] = s;
  __syncthreads();
  float tot = (acc4[0] + acc4[1]) + (acc4[2] + acc4[3]);
  float inv = tot > 0.f ? 1.f / tot : 0.f;
  u.x *= inv; u.y *= inv; u.z *= inv; u.w *= inv;
  p[threadIdx.x] = u;
  uint2 pk;
  pk.x = pk2(u.x, u.y);
  pk.y = pk2(u.z, u.w);
  *(uint2*)&wb[row * 1024 + threadIdx.x * 4] = pk;
}

extern "C" void kernel_launch(void* const* d_in, const int* in_sizes, int n_in,
                              void* d_out, int out_size, void* d_ws, size_t ws_size,
                              hipStream_t stream)
{
  const int*   inputs     = (const int*)d_in[0];
  const int*   dependency = (const int*)d_in[1];
  const float* embed      = (const float*)d_in[2];
  const float* dept       = (const float*)d_in[3];
  const float* Wq = (const float*)d_in[4];   const float* bq = (const float*)d_in[5];
  const float* Wk = (const float*)d_in[6];   const float* bk = (const float*)d_in[7];
  const float* Wv = (const float*)d_in[8];   const float* bvv = (const float*)d_in[9];
  const float* W1 = (const float*)d_in[10];  const float* b1 = (const float*)d_in[11];
  const float* W2 = (const float*)d_in[12];  const float* b2 = (const float*)d_in[13];

  float* out  = (float*)d_out;                       // wm [16,1024,512] fp32 (32 MB)
  float* wout = out + (size_t)8388608;               // weights [16,1024,1024] fp32 (64 MB)

  // ws (shorts): q / kx / WTcat+W1T+W2T (high-water 36.2 MB, as r5)
  unsigned short* ws   = (unsigned short*)d_ws;
  unsigned short* q    = ws;
  unsigned short* kx   = ws + 8388608;
  unsigned short* WTc  = ws + 16777216;
  unsigned short* W1T  = ws + 17563648;
  unsigned short* W2T  = ws + 17825792;
  unsigned short* wbf  = ws;                          // [16384,1024] bf16 (32 MB)
  unsigned short* h    = ws;                          // [16384,512] bf16

  // output regions used as staging (dead before final writes):
  unsigned short* x    = (unsigned short*)wout;       // [16384,512] bf16; E overwrites later
  unsigned short* v    = (unsigned short*)out;        // [16384,512] bf16 in wm region lo
  unsigned short* vT   = (unsigned short*)out + 8388608;  // [16,512,1024] bf16 in wm hi
  unsigned short* wmp  = (unsigned short*)out;        // [16384,512] bf16 (over dead v)

  // 128 KB dynamic LDS for the 8-phase kernels
  const int LDSB = 131072;
  hipFuncSetAttribute((const void*)gemm_qkv,    hipFuncAttributeMaxDynamicSharedMemorySize, LDSB);
  hipFuncSetAttribute((const void*)score_kernel, hipFuncAttributeMaxDynamicSharedMemorySize, LDSB);
  hipFuncSetAttribute((const void*)gemm2<0, 0>, hipFuncAttributeMaxDynamicSharedMemorySize, LDSB);
  hipFuncSetAttribute((const void*)gemm2<0, 1>, hipFuncAttributeMaxDynamicSharedMemorySize, LDSB);
  hipFuncSetAttribute((const void*)gemm2<1, 0>, hipFuncAttributeMaxDynamicSharedMemorySize, LDSB);

  dim3 blk(256), blk5(512);

  trans_w<<<dim3(16, 16, 5), blk, 0, stream>>>(Wq, Wk, Wv, W1, W2, WTc);
  build_x<<<dim3(4096), blk, 0, stream>>>(embed, inputs, x);

  // 256^2 tiles: qkv (6,64) = 384 blocks
  gemm_qkv<<<dim3(6, 64, 1), blk5, LDSB, stream>>>(x, WTc, bq, bk, bvv, q, kx, v);

  // score: (4,4,16) = 256 blocks
  score_kernel<<<dim3(4, 4, 16), blk5, LDSB, stream>>>(q, kx, dependency, dept, wout);

  trans_v<<<dim3(16, 32, 16), blk, 0, stream>>>(v, vT);

  normalize_rows<<<dim3(16384), blk, 0, stream>>>(wout, wbf);

  // wm_pre = weights @ v   (bf16 x bf16, batched): (2,4,16) = 128 blocks
  gemm2<0, 0><<<dim3(2, 4, 16), blk5, LDSB, stream>>>(wbf, vT, nullptr, wmp,
                                                      512, 1024, 1024L * 1024, 512L * 1024, 1024L * 512);
  // h = tanh(wm_pre @ W1^T + b1): (2,64) = 128 blocks
  gemm2<0, 1><<<dim3(2, 64, 1), blk5, LDSB, stream>>>(wmp, W1T, b1, h, 512, 512, 0, 0, 0);
  // wm = h @ W2^T + b2  (fp32, overwrites wmp/vT staging -- both dead)
  gemm2<1, 0><<<dim3(2, 64, 1), blk5, LDSB, stream>>>(h, W2T, b2, out, 512, 512, 0, 0, 0);
}